// Round 1
// baseline (672.037 us; speedup 1.0000x reference)
//
#include <hip/hip_runtime.h>
#include <cstdint>
#include <cstddef>

// Problem constants (from reference: N_NODES, N_EDGES, IN_FT, HID, N_LAYERS)
#define NN 50000
#define NE 800000
#define FIN 256
#define HD 128
#define NEG_SLOPE 0.2f

// ---------------------------------------------------------------- utilities

__global__ void k_zero_i32(int* __restrict__ p, int n) {
    int i = blockIdx.x * blockDim.x + threadIdx.x;
    if (i < n) p[i] = 0;
}

__global__ void k_copy_i32(const int* __restrict__ a, int* __restrict__ b, int n) {
    int i = blockIdx.x * blockDim.x + threadIdx.x;
    if (i < n) b[i] = a[i];
}

// ------------------------------------------------------------- CSR build

__global__ void k_count(const int* __restrict__ dst, int* __restrict__ cnt) {
    int e = blockIdx.x * blockDim.x + threadIdx.x;
    if (e < NE) atomicAdd(&cnt[dst[e]], 1);
}

// single-workgroup chunked inclusive scan: row_ptr[0]=0, row_ptr[i+1]=sum cnt[0..i]
__global__ __launch_bounds__(1024) void k_scan(const int* __restrict__ cnt,
                                               int* __restrict__ row_ptr, int n) {
    __shared__ int buf[1024];
    __shared__ int carry_s;
    int tid = threadIdx.x;
    if (tid == 0) { carry_s = 0; row_ptr[0] = 0; }
    __syncthreads();
    for (int base = 0; base < n; base += 1024) {
        int i = base + tid;
        buf[tid] = (i < n) ? cnt[i] : 0;
        __syncthreads();
        #pragma unroll
        for (int o = 1; o < 1024; o <<= 1) {
            int t = (tid >= o) ? buf[tid - o] : 0;
            __syncthreads();
            buf[tid] += t;
            __syncthreads();
        }
        int c = carry_s;
        if (i < n) row_ptr[i + 1] = buf[tid] + c;
        __syncthreads();
        if (tid == 1023) carry_s = c + buf[1023];
        __syncthreads();
    }
}

__global__ void k_scatter(const int* __restrict__ src, const int* __restrict__ dst,
                          const float* __restrict__ ew, int* __restrict__ cursor,
                          int* __restrict__ col, float* __restrict__ wsrt) {
    int e = blockIdx.x * blockDim.x + threadIdx.x;
    if (e < NE) {
        int d = dst[e];
        int pos = atomicAdd(&cursor[d], 1);
        col[pos]  = src[e];
        wsrt[pos] = ew[e];
    }
}

// ------------------------------------------------------------- fp32 GEMM
// C[M][128] = A[M][K] @ B[K][128] (+ bias). BM=128, BN=128, BK=16,
// 256 threads, 8x8 microtile per thread. No fp32 MFMA on CDNA4 -> VALU GEMM.

template <int K>
__global__ __launch_bounds__(256) void k_gemm(const float* __restrict__ A,
                                              const float* __restrict__ B,
                                              const float* __restrict__ bias,
                                              float* __restrict__ C, int M) {
    constexpr int BM = 128, BN = 128, BK = 16;
    __shared__ float As[BK][BM + 4];   // k-major, padded
    __shared__ float Bs[BK][BN];

    const int tid = threadIdx.x;
    const int block_row = blockIdx.x * BM;
    const int tr = tid >> 4;            // 0..15 row group
    const int tc = tid & 15;            // 0..15 col group
    const int row0 = tr * 8, col0 = tc * 8;

    float acc[8][8] = {};

    for (int kt = 0; kt < K / BK; ++kt) {
        // stage A tile (128 rows x 16 k), transposed into LDS
        #pragma unroll
        for (int u = 0; u < 2; ++u) {
            int f4 = tid * 2 + u;           // 0..511
            int ar = f4 >> 2;               // row within tile
            int ak = (f4 & 3) * 4;          // k offset (float4)
            int gr = block_row + ar;
            float4 v = make_float4(0.f, 0.f, 0.f, 0.f);
            if (gr < M)
                v = *reinterpret_cast<const float4*>(A + (size_t)gr * K + kt * BK + ak);
            As[ak + 0][ar] = v.x; As[ak + 1][ar] = v.y;
            As[ak + 2][ar] = v.z; As[ak + 3][ar] = v.w;
        }
        // stage B tile (16 x 128)
        #pragma unroll
        for (int u = 0; u < 2; ++u) {
            int f4 = tid * 2 + u;
            int br = f4 >> 5;               // 32 float4 per row
            int bc = (f4 & 31) * 4;
            *reinterpret_cast<float4*>(&Bs[br][bc]) =
                *reinterpret_cast<const float4*>(B + (size_t)(kt * BK + br) * BN + bc);
        }
        __syncthreads();
        #pragma unroll
        for (int kk = 0; kk < BK; ++kk) {
            float a[8], b[8];
            #pragma unroll
            for (int i = 0; i < 8; ++i) a[i] = As[kk][row0 + i];
            #pragma unroll
            for (int j = 0; j < 8; ++j) b[j] = Bs[kk][col0 + j];
            #pragma unroll
            for (int i = 0; i < 8; ++i)
                #pragma unroll
                for (int j = 0; j < 8; ++j)
                    acc[i][j] = fmaf(a[i], b[j], acc[i][j]);
        }
        __syncthreads();
    }

    #pragma unroll
    for (int i = 0; i < 8; ++i) {
        int gr = block_row + row0 + i;
        if (gr >= M) continue;
        #pragma unroll
        for (int j = 0; j < 8; j += 4) {
            float4 v;
            v.x = acc[i][j + 0]; v.y = acc[i][j + 1];
            v.z = acc[i][j + 2]; v.w = acc[i][j + 3];
            if (bias) {
                v.x += bias[col0 + j + 0]; v.y += bias[col0 + j + 1];
                v.z += bias[col0 + j + 2]; v.w += bias[col0 + j + 3];
            }
            *reinterpret_cast<float4*>(C + (size_t)gr * BN + col0 + j) = v;
        }
    }
}

// -------------------------------------------------- per-row attention dots
// as_[i] = hp[i] . att_src ; ad_[i] = hp[i] . att_dst   (one wave per row)

__global__ void k_att(const float* __restrict__ hp,
                      const float* __restrict__ att_s, const float* __restrict__ att_d,
                      float* __restrict__ as_, float* __restrict__ ad_) {
    int wave = (blockIdx.x * blockDim.x + threadIdx.x) >> 6;
    int lane = threadIdx.x & 63;
    if (wave >= NN) return;
    const float* row = hp + (size_t)wave * HD;
    float s = row[lane] * att_s[lane] + row[lane + 64] * att_s[lane + 64];
    float d = row[lane] * att_d[lane] + row[lane + 64] * att_d[lane + 64];
    #pragma unroll
    for (int o = 32; o > 0; o >>= 1) {
        s += __shfl_xor(s, o);
        d += __shfl_xor(d, o);
    }
    if (lane == 0) { as_[wave] = s; ad_[wave] = d; }
}

// ---------------------------------------------- fused softmax-aggregation
// One wave per destination node. mode: 0 = first layer (h += agg; out = h),
// 1 = middle (h += agg; out = max(out, h)), 2 = last (out = max(out, agg+b)).

__global__ __launch_bounds__(256) void k_agg(const float* __restrict__ hp,
                                             float* __restrict__ h,        // in/out residual
                                             const float* __restrict__ as_,
                                             const float* __restrict__ ad_,
                                             const int* __restrict__ row_ptr,
                                             const int* __restrict__ col,
                                             const float* __restrict__ wsrt,
                                             const float* __restrict__ bias,
                                             float* __restrict__ out, int mode) {
    int wave = (blockIdx.x * blockDim.x + threadIdx.x) >> 6;
    int lane = threadIdx.x & 63;
    if (wave >= NN) return;
    const int d = wave;
    const int beg = row_ptr[d], end = row_ptr[d + 1];
    const float adv = ad_[d];

    // pass 1: segment max of leaky_relu(as[src] + ad[dst])
    float mloc = -INFINITY;
    for (int p = beg + lane; p < end; p += 64) {
        float l = as_[col[p]] + adv;
        l = (l >= 0.f) ? l : NEG_SLOPE * l;
        mloc = fmaxf(mloc, l);
    }
    #pragma unroll
    for (int o = 32; o > 0; o >>= 1) mloc = fmaxf(mloc, __shfl_xor(mloc, o));
    const float m = (end > beg) ? mloc : 0.f;   // empty-segment isfinite guard

    // pass 2: weighted feature accumulation (all lanes, 2 features each)
    float acc0 = 0.f, acc1 = 0.f, denom = 0.f;
    for (int p = beg; p < end; ++p) {
        int s = col[p];
        float l = as_[s] + adv;
        l = (l >= 0.f) ? l : NEG_SLOPE * l;
        float w = __expf(l - m) * wsrt[p];
        denom += w;
        const float* hprow = hp + (size_t)s * HD;
        acc0 = fmaf(w, hprow[lane],      acc0);
        acc1 = fmaf(w, hprow[lane + 64], acc1);
    }
    const float inv = 1.f / (denom + 1e-16f);
    float r0 = acc0 * inv + bias[lane];
    float r1 = acc1 * inv + bias[lane + 64];

    const size_t off = (size_t)d * HD;
    if (mode == 2) {
        out[off + lane]      = fmaxf(out[off + lane],      r0);
        out[off + lane + 64] = fmaxf(out[off + lane + 64], r1);
    } else {
        float h0 = h[off + lane]      + r0;
        float h1 = h[off + lane + 64] + r1;
        h[off + lane]      = h0;
        h[off + lane + 64] = h1;
        if (mode == 0) {
            out[off + lane]      = h0;
            out[off + lane + 64] = h1;
        } else {
            out[off + lane]      = fmaxf(out[off + lane],      h0);
            out[off + lane + 64] = fmaxf(out[off + lane + 64], h1);
        }
    }
}

// ---------------------------------------------------------------- launch

extern "C" void kernel_launch(void* const* d_in, const int* in_sizes, int n_in,
                              void* d_out, int out_size, void* d_ws, size_t ws_size,
                              hipStream_t stream) {
    const float* x        = (const float*)d_in[0];          // [NN][FIN]
    const int*   ei       = (const int*)d_in[1];            // [2][NE]
    const float* ew       = (const float*)d_in[2];          // [NE]
    /* d_in[3] = numNode (scalar), statically NN */
    const float* Wlin     = (const float*)d_in[4];          // [FIN][HD]
    const float* blin     = (const float*)d_in[5];          // [HD]
    const float* Wc       = (const float*)d_in[6];          // [3][HD][HD]
    const float* att_src  = (const float*)d_in[7];          // [3][HD]
    const float* att_dst  = (const float*)d_in[8];          // [3][HD]
    const float* bias_c   = (const float*)d_in[9];          // [3][HD]
    float* out = (float*)d_out;                              // [NN][HD]

    const int* src = ei;
    const int* dst = ei + NE;

    // workspace layout (f32/int32, ~58.4 MB total)
    char* w = (char*)d_ws;
    float* h       = (float*)w;                 w += (size_t)NN * HD * 4;
    float* hp      = (float*)w;                 w += (size_t)NN * HD * 4;
    float* as_     = (float*)w;                 w += (size_t)NN * 4;
    float* ad_     = (float*)w;                 w += (size_t)NN * 4;
    int*   row_ptr = (int*)w;                   w += (size_t)(NN + 1) * 4;
    int*   cursor  = (int*)w;                   w += (size_t)NN * 4;
    int*   col     = (int*)w;                   w += (size_t)NE * 4;
    float* wsrt    = (float*)w;                 w += (size_t)NE * 4;

    const int TB = 256;
    const int nblk_n = (NN + TB - 1) / TB;          // 196
    const int nblk_e = (NE + TB - 1) / TB;          // 3125
    const int nblk_w = (NN * 64 + TB - 1) / TB;     // 12500 (one wave per node)
    const int nblk_g = (NN + 127) / 128;            // 391

    // ---- CSR build (per call; deterministic up to fp add order) ----
    k_zero_i32<<<nblk_n, TB, 0, stream>>>(cursor, NN);
    k_count<<<nblk_e, TB, 0, stream>>>(dst, cursor);
    k_scan<<<1, 1024, 0, stream>>>(cursor, row_ptr, NN);
    k_copy_i32<<<nblk_n, TB, 0, stream>>>(row_ptr, cursor, NN);
    k_scatter<<<nblk_e, TB, 0, stream>>>(src, dst, ew, cursor, col, wsrt);

    // ---- input projection: h = x @ Wlin + blin ----
    k_gemm<FIN><<<nblk_g, TB, 0, stream>>>(x, Wlin, blin, h, NN);

    // ---- 3 GAT layers ----
    for (int layer = 0; layer < 3; ++layer) {
        k_gemm<HD><<<nblk_g, TB, 0, stream>>>(h, Wc + (size_t)layer * HD * HD,
                                              nullptr, hp, NN);
        k_att<<<nblk_w, TB, 0, stream>>>(hp, att_src + layer * HD,
                                         att_dst + layer * HD, as_, ad_);
        int mode = (layer == 0) ? 0 : (layer == 2 ? 2 : 1);
        k_agg<<<nblk_w, TB, 0, stream>>>(hp, h, as_, ad_, row_ptr, col, wsrt,
                                         bias_c + layer * HD, out, mode);
    }
}

// Round 2
// 532.532 us; speedup vs baseline: 1.2620x; 1.2620x over previous
//
#include <hip/hip_runtime.h>
#include <cstdint>
#include <cstddef>

// Problem constants (from reference: N_NODES, N_EDGES, IN_FT, HID, N_LAYERS)
#define NN 50000
#define NE 800000
#define FIN 256
#define HD 128
#define NEG_SLOPE 0.2f

// ---------------------------------------------------------------- utilities

__global__ void k_zero_i32(int* __restrict__ p, int n) {
    int i = blockIdx.x * blockDim.x + threadIdx.x;
    if (i < n) p[i] = 0;
}

__global__ void k_copy_i32(const int* __restrict__ a, int* __restrict__ b, int n) {
    int i = blockIdx.x * blockDim.x + threadIdx.x;
    if (i < n) b[i] = a[i];
}

// ------------------------------------------------------------- CSR build

__global__ void k_count(const int* __restrict__ dst, int* __restrict__ cnt) {
    int e = blockIdx.x * blockDim.x + threadIdx.x;
    if (e < NE) atomicAdd(&cnt[dst[e]], 1);
}

// single-workgroup chunked inclusive scan via wave shuffles (2 barriers/chunk)
__global__ __launch_bounds__(1024) void k_scan(const int* __restrict__ cnt,
                                               int* __restrict__ row_ptr, int n) {
    __shared__ int wsum[16];
    __shared__ int carry_s;
    const int tid  = threadIdx.x;
    const int wid  = tid >> 6;
    const int lane = tid & 63;
    if (tid == 0) { carry_s = 0; row_ptr[0] = 0; }
    __syncthreads();
    for (int base = 0; base < n; base += 1024) {
        int i = base + tid;
        int x = (i < n) ? cnt[i] : 0;
        #pragma unroll
        for (int o = 1; o < 64; o <<= 1) {
            int t = __shfl_up(x, o);
            if (lane >= o) x += t;
        }
        if (lane == 63) wsum[wid] = x;
        __syncthreads();
        int wo = 0;
        for (int k = 0; k < wid; ++k) wo += wsum[k];   // uniform LDS broadcast reads
        int c = carry_s;
        if (i < n) row_ptr[i + 1] = x + wo + c;
        __syncthreads();
        if (tid == 1023) carry_s = c + wo + x;
    }
}

__global__ void k_scatter(const int* __restrict__ src, const int* __restrict__ dst,
                          const float* __restrict__ ew, int* __restrict__ cursor,
                          int* __restrict__ col, float* __restrict__ wsrt) {
    int e = blockIdx.x * blockDim.x + threadIdx.x;
    if (e < NE) {
        int d = dst[e];
        int pos = atomicAdd(&cursor[d], 1);
        col[pos]  = src[e];
        wsrt[pos] = ew[e];
    }
}

// ------------------------------------------------------------- fp32 GEMM
// C[M][128] = A[M][K] @ B[K][128] (+ bias). BM=128, BN=128, BK=16,
// 256 threads, 8x8 microtile per thread. No fp32 MFMA on CDNA4 -> VALU GEMM.

template <int K>
__global__ __launch_bounds__(256) void k_gemm(const float* __restrict__ A,
                                              const float* __restrict__ B,
                                              const float* __restrict__ bias,
                                              float* __restrict__ C, int M) {
    constexpr int BM = 128, BN = 128, BK = 16;
    __shared__ float As[BK][BM + 4];   // k-major, padded
    __shared__ float Bs[BK][BN];

    const int tid = threadIdx.x;
    const int block_row = blockIdx.x * BM;
    const int tr = tid >> 4;            // 0..15 row group
    const int tc = tid & 15;            // 0..15 col group
    const int row0 = tr * 8, col0 = tc * 8;

    float acc[8][8] = {};

    for (int kt = 0; kt < K / BK; ++kt) {
        #pragma unroll
        for (int u = 0; u < 2; ++u) {
            int f4 = tid * 2 + u;           // 0..511
            int ar = f4 >> 2;               // row within tile
            int ak = (f4 & 3) * 4;          // k offset (float4)
            int gr = block_row + ar;
            float4 v = make_float4(0.f, 0.f, 0.f, 0.f);
            if (gr < M)
                v = *reinterpret_cast<const float4*>(A + (size_t)gr * K + kt * BK + ak);
            As[ak + 0][ar] = v.x; As[ak + 1][ar] = v.y;
            As[ak + 2][ar] = v.z; As[ak + 3][ar] = v.w;
        }
        #pragma unroll
        for (int u = 0; u < 2; ++u) {
            int f4 = tid * 2 + u;
            int br = f4 >> 5;               // 32 float4 per row
            int bc = (f4 & 31) * 4;
            *reinterpret_cast<float4*>(&Bs[br][bc]) =
                *reinterpret_cast<const float4*>(B + (size_t)(kt * BK + br) * BN + bc);
        }
        __syncthreads();
        #pragma unroll
        for (int kk = 0; kk < BK; ++kk) {
            float a[8], b[8];
            #pragma unroll
            for (int i = 0; i < 8; ++i) a[i] = As[kk][row0 + i];
            #pragma unroll
            for (int j = 0; j < 8; ++j) b[j] = Bs[kk][col0 + j];
            #pragma unroll
            for (int i = 0; i < 8; ++i)
                #pragma unroll
                for (int j = 0; j < 8; ++j)
                    acc[i][j] = fmaf(a[i], b[j], acc[i][j]);
        }
        __syncthreads();
    }

    #pragma unroll
    for (int i = 0; i < 8; ++i) {
        int gr = block_row + row0 + i;
        if (gr >= M) continue;
        #pragma unroll
        for (int j = 0; j < 8; j += 4) {
            float4 v;
            v.x = acc[i][j + 0]; v.y = acc[i][j + 1];
            v.z = acc[i][j + 2]; v.w = acc[i][j + 3];
            if (bias) {
                v.x += bias[col0 + j + 0]; v.y += bias[col0 + j + 1];
                v.z += bias[col0 + j + 2]; v.w += bias[col0 + j + 3];
            }
            *reinterpret_cast<float4*>(C + (size_t)gr * BN + col0 + j) = v;
        }
    }
}

// -------------------------------------------------- per-row attention dots

__global__ void k_att(const float* __restrict__ hp,
                      const float* __restrict__ att_s, const float* __restrict__ att_d,
                      float* __restrict__ as_, float* __restrict__ ad_) {
    int wave = (blockIdx.x * blockDim.x + threadIdx.x) >> 6;
    int lane = threadIdx.x & 63;
    if (wave >= NN) return;
    const float* row = hp + (size_t)wave * HD;
    float s = row[lane] * att_s[lane] + row[lane + 64] * att_s[lane + 64];
    float d = row[lane] * att_d[lane] + row[lane + 64] * att_d[lane + 64];
    #pragma unroll
    for (int o = 32; o > 0; o >>= 1) {
        s += __shfl_xor(s, o);
        d += __shfl_xor(d, o);
    }
    if (lane == 0) { as_[wave] = s; ad_[wave] = d; }
}

// ---------------------------------------------- fused softmax-aggregation
// One wave per destination node; lane l owns features {2l, 2l+1} (float2).
// Phase A (lane-parallel): per-edge softmax weights, no serial chains.
// Phase B: shfl-broadcast weights; only memory op is the independent,
// 4-deep-pipelined hp row gather.
// mode: 0 = first layer (h += agg; out = h), 1 = middle (h += agg;
// out = max(out, h)), 2 = last (out = max(out, agg + b)).

__global__ __launch_bounds__(256) void k_agg(const float* __restrict__ hp,
                                             float* __restrict__ h,
                                             const float* __restrict__ as_,
                                             const float* __restrict__ ad_,
                                             const int* __restrict__ row_ptr,
                                             const int* __restrict__ col,
                                             const float* __restrict__ wsrt,
                                             const float* __restrict__ bias,
                                             float* __restrict__ out, int mode) {
    int wave = (blockIdx.x * blockDim.x + threadIdx.x) >> 6;
    int lane = threadIdx.x & 63;
    if (wave >= NN) return;
    const int d = wave;
    const int beg = row_ptr[d], end = row_ptr[d + 1];
    const float adv = ad_[d];

    // pass 1: lane-parallel segment max of leaky_relu(as[src] + ad[dst])
    float mloc = -INFINITY;
    for (int p = beg + lane; p < end; p += 64) {
        float l = as_[col[p]] + adv;
        l = (l >= 0.f) ? l : NEG_SLOPE * l;
        mloc = fmaxf(mloc, l);
    }
    #pragma unroll
    for (int o = 32; o > 0; o >>= 1) mloc = fmaxf(mloc, __shfl_xor(mloc, o));
    const float m = (end > beg) ? mloc : 0.f;

    // pass 2: chunked weight computation + broadcast accumulation
    float ax = 0.f, ay = 0.f, dloc = 0.f;
    for (int base = beg; base < end; base += 64) {
        const int n = min(64, end - base);
        int   s = 0;
        float w = 0.f;
        if (lane < n) {
            s = col[base + lane];
            float l = as_[s] + adv;
            l = (l >= 0.f) ? l : NEG_SLOPE * l;
            w = __expf(l - m) * wsrt[base + lane];
        }
        dloc += w;

        int i = 0;
        for (; i + 3 < n; i += 4) {
            float w0 = __shfl(w, i),     w1 = __shfl(w, i + 1);
            float w2 = __shfl(w, i + 2), w3 = __shfl(w, i + 3);
            int   s0 = __shfl(s, i),     s1 = __shfl(s, i + 1);
            int   s2 = __shfl(s, i + 2), s3 = __shfl(s, i + 3);
            float2 v0 = *reinterpret_cast<const float2*>(hp + (size_t)s0 * HD + lane * 2);
            float2 v1 = *reinterpret_cast<const float2*>(hp + (size_t)s1 * HD + lane * 2);
            float2 v2 = *reinterpret_cast<const float2*>(hp + (size_t)s2 * HD + lane * 2);
            float2 v3 = *reinterpret_cast<const float2*>(hp + (size_t)s3 * HD + lane * 2);
            ax = fmaf(w0, v0.x, ax); ay = fmaf(w0, v0.y, ay);
            ax = fmaf(w1, v1.x, ax); ay = fmaf(w1, v1.y, ay);
            ax = fmaf(w2, v2.x, ax); ay = fmaf(w2, v2.y, ay);
            ax = fmaf(w3, v3.x, ax); ay = fmaf(w3, v3.y, ay);
        }
        for (; i < n; ++i) {
            float wi = __shfl(w, i);
            int   si = __shfl(s, i);
            float2 v = *reinterpret_cast<const float2*>(hp + (size_t)si * HD + lane * 2);
            ax = fmaf(wi, v.x, ax); ay = fmaf(wi, v.y, ay);
        }
    }
    #pragma unroll
    for (int o = 32; o > 0; o >>= 1) dloc += __shfl_xor(dloc, o);

    const float inv = 1.f / (dloc + 1e-16f);
    const float r0 = ax * inv + bias[lane * 2];
    const float r1 = ay * inv + bias[lane * 2 + 1];

    const size_t off = (size_t)d * HD + lane * 2;
    if (mode == 2) {
        float2 o = *reinterpret_cast<float2*>(out + off);
        o.x = fmaxf(o.x, r0); o.y = fmaxf(o.y, r1);
        *reinterpret_cast<float2*>(out + off) = o;
    } else {
        float2 hv = *reinterpret_cast<float2*>(h + off);
        hv.x += r0; hv.y += r1;
        *reinterpret_cast<float2*>(h + off) = hv;
        if (mode == 0) {
            *reinterpret_cast<float2*>(out + off) = hv;
        } else {
            float2 o = *reinterpret_cast<float2*>(out + off);
            o.x = fmaxf(o.x, hv.x); o.y = fmaxf(o.y, hv.y);
            *reinterpret_cast<float2*>(out + off) = o;
        }
    }
}

// ---------------------------------------------------------------- launch

extern "C" void kernel_launch(void* const* d_in, const int* in_sizes, int n_in,
                              void* d_out, int out_size, void* d_ws, size_t ws_size,
                              hipStream_t stream) {
    const float* x        = (const float*)d_in[0];          // [NN][FIN]
    const int*   ei       = (const int*)d_in[1];            // [2][NE]
    const float* ew       = (const float*)d_in[2];          // [NE]
    /* d_in[3] = numNode (scalar), statically NN */
    const float* Wlin     = (const float*)d_in[4];          // [FIN][HD]
    const float* blin     = (const float*)d_in[5];          // [HD]
    const float* Wc       = (const float*)d_in[6];          // [3][HD][HD]
    const float* att_src  = (const float*)d_in[7];          // [3][HD]
    const float* att_dst  = (const float*)d_in[8];          // [3][HD]
    const float* bias_c   = (const float*)d_in[9];          // [3][HD]
    float* out = (float*)d_out;                              // [NN][HD]

    const int* src = ei;
    const int* dst = ei + NE;

    // workspace layout (f32/int32, ~58.4 MB total)
    char* w = (char*)d_ws;
    float* h       = (float*)w;                 w += (size_t)NN * HD * 4;
    float* hp      = (float*)w;                 w += (size_t)NN * HD * 4;
    float* as_     = (float*)w;                 w += (size_t)NN * 4;
    float* ad_     = (float*)w;                 w += (size_t)NN * 4;
    int*   row_ptr = (int*)w;                   w += (size_t)(NN + 1) * 4;
    int*   cursor  = (int*)w;                   w += (size_t)NN * 4;
    int*   col     = (int*)w;                   w += (size_t)NE * 4;
    float* wsrt    = (float*)w;                 w += (size_t)NE * 4;

    const int TB = 256;
    const int nblk_n = (NN + TB - 1) / TB;          // 196
    const int nblk_e = (NE + TB - 1) / TB;          // 3125
    const int nblk_w = (NN * 64 + TB - 1) / TB;     // 12500 (one wave per node)
    const int nblk_g = (NN + 127) / 128;            // 391

    // ---- CSR build ----
    k_zero_i32<<<nblk_n, TB, 0, stream>>>(cursor, NN);
    k_count<<<nblk_e, TB, 0, stream>>>(dst, cursor);
    k_scan<<<1, 1024, 0, stream>>>(cursor, row_ptr, NN);
    k_copy_i32<<<nblk_n, TB, 0, stream>>>(row_ptr, cursor, NN);
    k_scatter<<<nblk_e, TB, 0, stream>>>(src, dst, ew, cursor, col, wsrt);

    // ---- input projection: h = x @ Wlin + blin ----
    k_gemm<FIN><<<nblk_g, TB, 0, stream>>>(x, Wlin, blin, h, NN);

    // ---- 3 GAT layers ----
    for (int layer = 0; layer < 3; ++layer) {
        k_gemm<HD><<<nblk_g, TB, 0, stream>>>(h, Wc + (size_t)layer * HD * HD,
                                              nullptr, hp, NN);
        k_att<<<nblk_w, TB, 0, stream>>>(hp, att_src + layer * HD,
                                         att_dst + layer * HD, as_, ad_);
        int mode = (layer == 0) ? 0 : (layer == 2 ? 2 : 1);
        k_agg<<<nblk_w, TB, 0, stream>>>(hp, h, as_, ad_, row_ptr, col, wsrt,
                                         bias_c + layer * HD, out, mode);
    }
}

// Round 3
// 417.555 us; speedup vs baseline: 1.6095x; 1.2754x over previous
//
#include <hip/hip_runtime.h>
#include <cstdint>
#include <cstddef>

// Problem constants (from reference)
#define NN 50000
#define NE 800000
#define FIN 256
#define HD 128
#define NEG_SLOPE 0.2f

typedef short s16x8 __attribute__((ext_vector_type(8)));   // 8 bf16 (4 VGPRs)
typedef float f32x4 __attribute__((ext_vector_type(4)));   // MFMA accumulator

__device__ inline ushort f2bf(float f) {                   // fp32 -> bf16 RTN-even
    uint32_t u = __float_as_uint(f);
    u += 0x7FFFu + ((u >> 16) & 1u);
    return (ushort)(u >> 16);
}
__device__ inline float bf2f(ushort h) {
    return __uint_as_float(((uint32_t)h) << 16);
}

// ---------------------------------------------------------------- utilities

__global__ void k_zero_i32(int* __restrict__ p, int n) {
    int i = blockIdx.x * blockDim.x + threadIdx.x;
    if (i < n) p[i] = 0;
}

__global__ void k_copy_i32(const int* __restrict__ a, int* __restrict__ b, int n) {
    int i = blockIdx.x * blockDim.x + threadIdx.x;
    if (i < n) b[i] = a[i];
}

// ------------------------------------------------------------- CSR build

__global__ void k_count(const int* __restrict__ dst, int* __restrict__ cnt) {
    int e = blockIdx.x * blockDim.x + threadIdx.x;
    if (e < NE) atomicAdd(&cnt[dst[e]], 1);
}

__global__ __launch_bounds__(1024) void k_scan(const int* __restrict__ cnt,
                                               int* __restrict__ row_ptr, int n) {
    __shared__ int wsum[16];
    __shared__ int carry_s;
    const int tid  = threadIdx.x;
    const int wid  = tid >> 6;
    const int lane = tid & 63;
    if (tid == 0) { carry_s = 0; row_ptr[0] = 0; }
    __syncthreads();
    for (int base = 0; base < n; base += 1024) {
        int i = base + tid;
        int x = (i < n) ? cnt[i] : 0;
        #pragma unroll
        for (int o = 1; o < 64; o <<= 1) {
            int t = __shfl_up(x, o);
            if (lane >= o) x += t;
        }
        if (lane == 63) wsum[wid] = x;
        __syncthreads();
        int wo = 0;
        for (int k = 0; k < wid; ++k) wo += wsum[k];
        int c = carry_s;
        if (i < n) row_ptr[i + 1] = x + wo + c;
        __syncthreads();
        if (tid == 1023) carry_s = c + wo + x;
    }
}

__global__ void k_scatter(const int* __restrict__ src, const int* __restrict__ dst,
                          const float* __restrict__ ew, int* __restrict__ cursor,
                          int* __restrict__ col, float* __restrict__ wsrt) {
    int e = blockIdx.x * blockDim.x + threadIdx.x;
    if (e < NE) {
        int d = dst[e];
        int pos = atomicAdd(&cursor[d], 1);
        col[pos]  = src[e];
        wsrt[pos] = ew[e];
    }
}

// -------------------------------------------- weight transpose + bf16 split
// W [K][HD] fp32 row-major -> Th/Tl [HD][K] bf16 (hi + residual-lo)

__global__ void k_split(const float* __restrict__ W, ushort* __restrict__ Th,
                        ushort* __restrict__ Tl, int K) {
    int idx = blockIdx.x * blockDim.x + threadIdx.x;   // = n*K + k
    if (idx >= K * HD) return;
    int n = idx / K, k = idx - n * K;
    float f = W[(size_t)k * HD + n];
    ushort hi = f2bf(f);
    Th[idx] = hi;
    Tl[idx] = f2bf(f - bf2f(hi));
}

// ----------------------------------------------------- MFMA split-bf16 GEMM
// C[M][128] = A[M][K] @ B[K][128] (+bias) via 16x16x32 bf16 MFMA,
// D = Ahi*Bhi + Ahi*Blo + Alo*Bhi  (~fp32 accuracy).
// BM=128, BK=32, 256 threads = 4 waves; wave w owns rows [w*32, w*32+32).
// A staged fp32->split bf16 in LDS (stride 40 -> 2-way-free b128 frag reads);
// B^T hi/lo read directly from global (L1/L2-resident).
// Optional fused epilogue: as_[r]=C[r].att_s, ad_[r]=C[r].att_d.

template <int K, bool ATT>
__global__ __launch_bounds__(256) void k_gemm_mfma(
    const float*  __restrict__ A,
    const ushort* __restrict__ Bh,     // [HD][K]
    const ushort* __restrict__ Bl,     // [HD][K]
    const float*  __restrict__ bias,   // null if none
    float*        __restrict__ Cf,     // fp32 out (null if unused)
    ushort*       __restrict__ Cb,     // bf16 out (null if unused)
    const float*  __restrict__ att_s, const float* __restrict__ att_d,
    float* __restrict__ as_, float* __restrict__ ad_,
    int M)
{
    constexpr int BM = 128, BK = 32;
    constexpr int LDW = 40;                       // LDS row stride (bf16 units)
    __shared__ ushort Ah[BM * LDW];
    __shared__ ushort Al[BM * LDW];

    const int tid  = threadIdx.x;
    const int lane = tid & 63;
    const int wid  = tid >> 6;
    const int blockRow = blockIdx.x * BM;

    const int srow  = tid >> 1;                   // staging: row, half-row
    const int shalf = tid & 1;

    const int fl = lane & 15;                     // frag row (A) / col (B)
    const int fg = lane >> 4;                     // frag k-group

    f32x4 acc[2][8] = {};

    for (int kt = 0; kt < K / BK; ++kt) {
        // ---- stage A tile: fp32 global -> split bf16 LDS ----
        {
            const int gr = blockRow + srow;
            float v[16];
            if (gr < M) {
                const float* ap = A + (size_t)gr * K + kt * BK + shalf * 16;
                #pragma unroll
                for (int u = 0; u < 4; ++u) {
                    float4 t = *reinterpret_cast<const float4*>(ap + u * 4);
                    v[u*4+0] = t.x; v[u*4+1] = t.y; v[u*4+2] = t.z; v[u*4+3] = t.w;
                }
            } else {
                #pragma unroll
                for (int u = 0; u < 16; ++u) v[u] = 0.f;
            }
            uint32_t hw[8], lw[8];
            #pragma unroll
            for (int u = 0; u < 8; ++u) {
                ushort h0 = f2bf(v[2*u]),   h1 = f2bf(v[2*u+1]);
                ushort l0 = f2bf(v[2*u]   - bf2f(h0));
                ushort l1 = f2bf(v[2*u+1] - bf2f(h1));
                hw[u] = (uint32_t)h0 | ((uint32_t)h1 << 16);
                lw[u] = (uint32_t)l0 | ((uint32_t)l1 << 16);
            }
            uint32_t* dh = reinterpret_cast<uint32_t*>(&Ah[srow * LDW + shalf * 16]);
            uint32_t* dl = reinterpret_cast<uint32_t*>(&Al[srow * LDW + shalf * 16]);
            *reinterpret_cast<uint4*>(dh)     = make_uint4(hw[0], hw[1], hw[2], hw[3]);
            *reinterpret_cast<uint4*>(dh + 4) = make_uint4(hw[4], hw[5], hw[6], hw[7]);
            *reinterpret_cast<uint4*>(dl)     = make_uint4(lw[0], lw[1], lw[2], lw[3]);
            *reinterpret_cast<uint4*>(dl + 4) = make_uint4(lw[4], lw[5], lw[6], lw[7]);
        }
        __syncthreads();

        // ---- A fragments (two 16-row tiles per wave) ----
        s16x8 a_h[2], a_l[2];
        #pragma unroll
        for (int rt = 0; rt < 2; ++rt) {
            int r = wid * 32 + rt * 16 + fl;
            a_h[rt] = *reinterpret_cast<const s16x8*>(&Ah[r * LDW + fg * 8]);
            a_l[rt] = *reinterpret_cast<const s16x8*>(&Al[r * LDW + fg * 8]);
        }

        // ---- 8 col-tiles, B frags straight from global ----
        #pragma unroll
        for (int ct = 0; ct < 8; ++ct) {
            const size_t boff = (size_t)(ct * 16 + fl) * K + kt * BK + fg * 8;
            s16x8 b_h = *reinterpret_cast<const s16x8*>(Bh + boff);
            s16x8 b_l = *reinterpret_cast<const s16x8*>(Bl + boff);
            #pragma unroll
            for (int rt = 0; rt < 2; ++rt) {
                acc[rt][ct] = __builtin_amdgcn_mfma_f32_16x16x32_bf16(a_h[rt], b_h, acc[rt][ct], 0, 0, 0);
                acc[rt][ct] = __builtin_amdgcn_mfma_f32_16x16x32_bf16(a_h[rt], b_l, acc[rt][ct], 0, 0, 0);
                acc[rt][ct] = __builtin_amdgcn_mfma_f32_16x16x32_bf16(a_l[rt], b_h, acc[rt][ct], 0, 0, 0);
            }
        }
        __syncthreads();
    }

    // ---- epilogue: C/D layout col = lane&15 (+16*ct), row = (lane>>4)*4+reg ----
    float bval[8];
    #pragma unroll
    for (int ct = 0; ct < 8; ++ct) bval[ct] = bias ? bias[ct * 16 + fl] : 0.f;
    float asv[8], adv[8];
    if (ATT) {
        #pragma unroll
        for (int ct = 0; ct < 8; ++ct) {
            asv[ct] = att_s[ct * 16 + fl];
            adv[ct] = att_d[ct * 16 + fl];
        }
    }

    #pragma unroll
    for (int rt = 0; rt < 2; ++rt) {
        const int rbase = blockRow + wid * 32 + rt * 16 + fg * 4;
        #pragma unroll
        for (int r = 0; r < 4; ++r) {
            const int row = rbase + r;
            const bool ok = row < M;
            float sv = 0.f, dv = 0.f;
            #pragma unroll
            for (int ct = 0; ct < 8; ++ct) {
                float val = acc[rt][ct][r] + bval[ct];
                if (ATT) { sv = fmaf(val, asv[ct], sv); dv = fmaf(val, adv[ct], dv); }
                if (ok) {
                    if (Cf) Cf[(size_t)row * HD + ct * 16 + fl] = val;
                    if (Cb) Cb[(size_t)row * HD + ct * 16 + fl] = f2bf(val);
                }
            }
            if (ATT) {
                #pragma unroll
                for (int o = 1; o < 16; o <<= 1) {
                    sv += __shfl_xor(sv, o);
                    dv += __shfl_xor(dv, o);
                }
                if (fl == 0 && ok) { as_[row] = sv; ad_[row] = dv; }
            }
        }
    }
}

// ---------------------------------------------- fused softmax-aggregation
// One wave per destination node; lane l owns features {2l, 2l+1}.
// hp rows are bf16 (halves gather traffic); accumulation in fp32.

__global__ __launch_bounds__(256) void k_agg(const ushort* __restrict__ hpb,
                                             float* __restrict__ h,
                                             const float* __restrict__ as_,
                                             const float* __restrict__ ad_,
                                             const int* __restrict__ row_ptr,
                                             const int* __restrict__ col,
                                             const float* __restrict__ wsrt,
                                             const float* __restrict__ bias,
                                             float* __restrict__ out, int mode) {
    int wave = (blockIdx.x * blockDim.x + threadIdx.x) >> 6;
    int lane = threadIdx.x & 63;
    if (wave >= NN) return;
    const int d = wave;
    const int beg = row_ptr[d], end = row_ptr[d + 1];
    const float adv = ad_[d];

    // pass 1: lane-parallel segment max of leaky_relu(as[src] + ad[dst])
    float mloc = -INFINITY;
    for (int p = beg + lane; p < end; p += 64) {
        float l = as_[col[p]] + adv;
        l = (l >= 0.f) ? l : NEG_SLOPE * l;
        mloc = fmaxf(mloc, l);
    }
    #pragma unroll
    for (int o = 32; o > 0; o >>= 1) mloc = fmaxf(mloc, __shfl_xor(mloc, o));
    const float m = (end > beg) ? mloc : 0.f;

    // pass 2: chunked weights + broadcast accumulation (4-deep gather pipeline)
    float ax = 0.f, ay = 0.f, dloc = 0.f;
    for (int base = beg; base < end; base += 64) {
        const int n = min(64, end - base);
        int   s = 0;
        float w = 0.f;
        if (lane < n) {
            s = col[base + lane];
            float l = as_[s] + adv;
            l = (l >= 0.f) ? l : NEG_SLOPE * l;
            w = __expf(l - m) * wsrt[base + lane];
        }
        dloc += w;

        int i = 0;
        for (; i + 3 < n; i += 4) {
            float w0 = __shfl(w, i),     w1 = __shfl(w, i + 1);
            float w2 = __shfl(w, i + 2), w3 = __shfl(w, i + 3);
            int   s0 = __shfl(s, i),     s1 = __shfl(s, i + 1);
            int   s2 = __shfl(s, i + 2), s3 = __shfl(s, i + 3);
            uint32_t p0 = *reinterpret_cast<const uint32_t*>(hpb + (size_t)s0 * HD + lane * 2);
            uint32_t p1 = *reinterpret_cast<const uint32_t*>(hpb + (size_t)s1 * HD + lane * 2);
            uint32_t p2 = *reinterpret_cast<const uint32_t*>(hpb + (size_t)s2 * HD + lane * 2);
            uint32_t p3 = *reinterpret_cast<const uint32_t*>(hpb + (size_t)s3 * HD + lane * 2);
            ax = fmaf(w0, bf2f((ushort)p0), ax); ay = fmaf(w0, bf2f((ushort)(p0 >> 16)), ay);
            ax = fmaf(w1, bf2f((ushort)p1), ax); ay = fmaf(w1, bf2f((ushort)(p1 >> 16)), ay);
            ax = fmaf(w2, bf2f((ushort)p2), ax); ay = fmaf(w2, bf2f((ushort)(p2 >> 16)), ay);
            ax = fmaf(w3, bf2f((ushort)p3), ax); ay = fmaf(w3, bf2f((ushort)(p3 >> 16)), ay);
        }
        for (; i < n; ++i) {
            float wi = __shfl(w, i);
            int   si = __shfl(s, i);
            uint32_t pv = *reinterpret_cast<const uint32_t*>(hpb + (size_t)si * HD + lane * 2);
            ax = fmaf(wi, bf2f((ushort)pv), ax); ay = fmaf(wi, bf2f((ushort)(pv >> 16)), ay);
        }
    }
    #pragma unroll
    for (int o = 32; o > 0; o >>= 1) dloc += __shfl_xor(dloc, o);

    const float inv = 1.f / (dloc + 1e-16f);
    const float r0 = ax * inv + bias[lane * 2];
    const float r1 = ay * inv + bias[lane * 2 + 1];

    const size_t off = (size_t)d * HD + lane * 2;
    if (mode == 2) {
        float2 o = *reinterpret_cast<float2*>(out + off);
        o.x = fmaxf(o.x, r0); o.y = fmaxf(o.y, r1);
        *reinterpret_cast<float2*>(out + off) = o;
    } else {
        float2 hv = *reinterpret_cast<float2*>(h + off);
        hv.x += r0; hv.y += r1;
        *reinterpret_cast<float2*>(h + off) = hv;
        if (mode == 0) {
            *reinterpret_cast<float2*>(out + off) = hv;
        } else {
            float2 o = *reinterpret_cast<float2*>(out + off);
            o.x = fmaxf(o.x, hv.x); o.y = fmaxf(o.y, hv.y);
            *reinterpret_cast<float2*>(out + off) = o;
        }
    }
}

// ---------------------------------------------------------------- launch

extern "C" void kernel_launch(void* const* d_in, const int* in_sizes, int n_in,
                              void* d_out, int out_size, void* d_ws, size_t ws_size,
                              hipStream_t stream) {
    const float* x        = (const float*)d_in[0];          // [NN][FIN]
    const int*   ei       = (const int*)d_in[1];            // [2][NE]
    const float* ew       = (const float*)d_in[2];          // [NE]
    /* d_in[3] = numNode scalar = NN */
    const float* Wlin     = (const float*)d_in[4];          // [FIN][HD]
    const float* blin     = (const float*)d_in[5];          // [HD]
    const float* Wc       = (const float*)d_in[6];          // [3][HD][HD]
    const float* att_src  = (const float*)d_in[7];          // [3][HD]
    const float* att_dst  = (const float*)d_in[8];          // [3][HD]
    const float* bias_c   = (const float*)d_in[9];          // [3][HD]
    float* out = (float*)d_out;                              // [NN][HD]

    const int* src = ei;
    const int* dst = ei + NE;

    // workspace layout (16B-aligned blocks)
    char* w = (char*)d_ws;
    float*  h       = (float*)w;   w += (size_t)NN * HD * 4;        // 25.6 MB
    ushort* hpb     = (ushort*)w;  w += (size_t)NN * HD * 2;        // 12.8 MB
    float*  as_     = (float*)w;   w += (size_t)NN * 4;
    float*  ad_     = (float*)w;   w += (size_t)NN * 4;
    int*    row_ptr = (int*)w;     w += (size_t)(NN + 4) * 4;
    int*    cursor  = (int*)w;     w += (size_t)NN * 4;
    int*    col     = (int*)w;     w += (size_t)NE * 4;
    float*  wsrt    = (float*)w;   w += (size_t)NE * 4;
    ushort* WTh     = (ushort*)w;  w += (size_t)(HD * FIN + 3 * HD * HD) * 2;
    ushort* WTl     = (ushort*)w;  w += (size_t)(HD * FIN + 3 * HD * HD) * 2;
    // per-matrix offsets inside WTh/WTl
    ushort* WlinTh = WTh,                 *WlinTl = WTl;
    ushort* WcTh   = WTh + HD * FIN,      *WcTl   = WTl + HD * FIN;

    const int TB = 256;
    const int nblk_n = (NN + TB - 1) / TB;
    const int nblk_e = (NE + TB - 1) / TB;
    const int nblk_w = (NN * 64 + TB - 1) / TB;      // one wave per node
    const int nblk_g = (NN + 127) / 128;             // 391

    // ---- weight transpose + split (tiny) ----
    k_split<<<(HD * FIN + TB - 1) / TB, TB, 0, stream>>>(Wlin, WlinTh, WlinTl, FIN);
    for (int l = 0; l < 3; ++l)
        k_split<<<(HD * HD + TB - 1) / TB, TB, 0, stream>>>(
            Wc + (size_t)l * HD * HD, WcTh + (size_t)l * HD * HD,
            WcTl + (size_t)l * HD * HD, HD);

    // ---- CSR build ----
    k_zero_i32<<<nblk_n, TB, 0, stream>>>(cursor, NN);
    k_count<<<nblk_e, TB, 0, stream>>>(dst, cursor);
    k_scan<<<1, 1024, 0, stream>>>(cursor, row_ptr, NN);
    k_copy_i32<<<nblk_n, TB, 0, stream>>>(row_ptr, cursor, NN);
    k_scatter<<<nblk_e, TB, 0, stream>>>(src, dst, ew, cursor, col, wsrt);

    // ---- input projection: h = x @ Wlin + blin (fp32 out) ----
    k_gemm_mfma<FIN, false><<<nblk_g, TB, 0, stream>>>(
        x, WlinTh, WlinTl, blin, h, nullptr, nullptr, nullptr, nullptr, nullptr, NN);

    // ---- 3 GAT layers ----
    for (int layer = 0; layer < 3; ++layer) {
        k_gemm_mfma<HD, true><<<nblk_g, TB, 0, stream>>>(
            h, WcTh + (size_t)layer * HD * HD, WcTl + (size_t)layer * HD * HD,
            nullptr, nullptr, hpb,
            att_src + layer * HD, att_dst + layer * HD, as_, ad_, NN);
        int mode = (layer == 0) ? 0 : (layer == 2 ? 2 : 1);
        k_agg<<<nblk_w, TB, 0, stream>>>(hpb, h, as_, ad_, row_ptr, col, wsrt,
                                         bias_c + layer * HD, out, mode);
    }
}

// Round 4
// 314.353 us; speedup vs baseline: 2.1378x; 1.3283x over previous
//
#include <hip/hip_runtime.h>
#include <cstdint>
#include <cstddef>

// Problem constants (from reference)
#define NN 50000
#define NE 800000
#define FIN 256
#define HD 128
#define NEG_SLOPE 0.2f

// CSR-build binning parameters
#define NBK 196          // buckets of 256 nodes: ceil(50000/256)
#define NCH 98           // edge chunks
#define CHUNK 8192       // edges per chunk (98*8192 >= 800000)

typedef short s16x8 __attribute__((ext_vector_type(8)));   // 8 bf16 (4 VGPRs)
typedef float f32x4 __attribute__((ext_vector_type(4)));   // MFMA accumulator

__device__ inline ushort f2bf(float f) {                   // fp32 -> bf16 RTN-even
    uint32_t u = __float_as_uint(f);
    u += 0x7FFFu + ((u >> 16) & 1u);
    return (ushort)(u >> 16);
}
__device__ inline float bf2f(ushort h) {
    return __uint_as_float(((uint32_t)h) << 16);
}

// ------------------------------------------------------------- CSR build
// bucket = dst >> 8. No global atomics anywhere:
// k_bhist   : per-(chunk,bucket) histogram matrix bhist[NCH][NBK]
// k_bscan   : in-place exclusive prefix -> per-(chunk,bucket) base offsets,
//             bucket starts bbeg[NBK+1], row_ptr[NN]=NE
// k_binscatter: chunk edges -> bucket-grouped packed array epk (LDS cursors)
// k_build   : per-bucket node counts + scan -> row_ptr, then col/wsrt scatter
//             into a single-XCD 32KB region (LDS cursors)

__global__ __launch_bounds__(1024) void k_bhist(const int* __restrict__ dst,
                                                int* __restrict__ bhist) {
    __shared__ int hist[NBK];
    const int tid = threadIdx.x, blk = blockIdx.x;
    if (tid < NBK) hist[tid] = 0;
    __syncthreads();
    const int e0 = blk * CHUNK;
    #pragma unroll
    for (int u = 0; u < CHUNK / 1024; ++u) {
        int e = e0 + u * 1024 + tid;
        if (e < NE) atomicAdd(&hist[dst[e] >> 8], 1);
    }
    __syncthreads();
    if (tid < NBK) bhist[blk * NBK + tid] = hist[tid];
}

__global__ __launch_bounds__(256) void k_bscan(int* __restrict__ bhist,
                                               int* __restrict__ bbeg,
                                               int* __restrict__ row_ptr) {
    __shared__ int wsum[4];
    const int tid = threadIdx.x;
    int tot = 0;
    if (tid < NBK) {
        for (int c = 0; c < NCH; ++c) {           // coalesced across tid
            int t = bhist[c * NBK + tid];
            bhist[c * NBK + tid] = tot;           // per-bucket chunk prefix
            tot += t;
        }
    }
    const int lane = tid & 63, wid = tid >> 6;
    int x = tot;
    #pragma unroll
    for (int o = 1; o < 64; o <<= 1) {
        int t = __shfl_up(x, o);
        if (lane >= o) x += t;
    }
    if (lane == 63) wsum[wid] = x;
    __syncthreads();
    int wo = 0;
    for (int k = 0; k < wid; ++k) wo += wsum[k];
    const int excl = x - tot + wo;                // bucket start offset
    if (tid < NBK) bbeg[tid] = excl;
    if (tid == 0) { bbeg[NBK] = NE; row_ptr[NN] = NE; }
    __syncthreads();
    if (tid < NBK)
        for (int c = 0; c < NCH; ++c) bhist[c * NBK + tid] += excl;
}

__global__ __launch_bounds__(1024) void k_binscatter(const int* __restrict__ src,
                                                     const int* __restrict__ dst,
                                                     const float* __restrict__ ew,
                                                     const int* __restrict__ bhist,
                                                     uint2* __restrict__ epk) {
    __shared__ int base[NBK];
    __shared__ int lcur[NBK];
    const int tid = threadIdx.x, blk = blockIdx.x;
    if (tid < NBK) { base[tid] = bhist[blk * NBK + tid]; lcur[tid] = 0; }
    __syncthreads();
    const int e0 = blk * CHUNK;
    #pragma unroll
    for (int u = 0; u < CHUNK / 1024; ++u) {
        int e = e0 + u * 1024 + tid;
        if (e < NE) {
            int d = dst[e];
            int s = src[e];
            float w = ew[e];
            int b = d >> 8;
            int pos = base[b] + atomicAdd(&lcur[b], 1);   // LDS atomic only
            epk[pos] = make_uint2((uint32_t)s | ((uint32_t)(d & 255) << 16),
                                  __float_as_uint(w));
        }
    }
}

__global__ __launch_bounds__(256) void k_build(const uint2* __restrict__ epk,
                                               const int* __restrict__ bbeg,
                                               int* __restrict__ row_ptr,
                                               int* __restrict__ col,
                                               float* __restrict__ wsrt) {
    __shared__ int cnt[256];
    __shared__ int cur[256];
    __shared__ int wsum[4];
    const int tid = threadIdx.x, b = blockIdx.x;
    const int n0 = b << 8;
    const int ebeg = bbeg[b], eend = bbeg[b + 1];
    cnt[tid] = 0;
    __syncthreads();
    for (int e = ebeg + tid; e < eend; e += 256)
        atomicAdd(&cnt[(epk[e].x >> 16) & 255], 1);
    __syncthreads();
    const int v = cnt[tid];
    const int lane = tid & 63, wid = tid >> 6;
    int x = v;
    #pragma unroll
    for (int o = 1; o < 64; o <<= 1) {
        int t = __shfl_up(x, o);
        if (lane >= o) x += t;
    }
    if (lane == 63) wsum[wid] = x;
    __syncthreads();
    int wo = 0;
    for (int k = 0; k < wid; ++k) wo += wsum[k];
    const int excl = ebeg + x - v + wo;           // node segment start
    if (n0 + tid < NN) row_ptr[n0 + tid] = excl;
    cur[tid] = excl;
    __syncthreads();
    for (int e = ebeg + tid; e < eend; e += 256) {
        uint2 p = epk[e];
        int dl = (p.x >> 16) & 255;
        int pos = atomicAdd(&cur[dl], 1);
        col[pos]  = (int)(p.x & 0xFFFFu);
        wsrt[pos] = __uint_as_float(p.y);
    }
}

// -------------------------------------------- weight transpose + bf16 split
// W [K][HD] fp32 row-major -> Th/Tl [HD][K] bf16 (hi + residual-lo)

__global__ void k_split(const float* __restrict__ W, ushort* __restrict__ Th,
                        ushort* __restrict__ Tl, int K) {
    int idx = blockIdx.x * blockDim.x + threadIdx.x;   // = n*K + k
    if (idx >= K * HD) return;
    int n = idx / K, k = idx - n * K;
    float f = W[(size_t)k * HD + n];
    ushort hi = f2bf(f);
    Th[idx] = hi;
    Tl[idx] = f2bf(f - bf2f(hi));
}

// ----------------------------------------------------- MFMA split-bf16 GEMM
// C[M][128] = A[M][K] @ B[K][128] (+bias) via 16x16x32 bf16 MFMA,
// D = Ahi*Bhi + Ahi*Blo + Alo*Bhi  (~fp32 accuracy).

template <int K, bool ATT>
__global__ __launch_bounds__(256) void k_gemm_mfma(
    const float*  __restrict__ A,
    const ushort* __restrict__ Bh,     // [HD][K]
    const ushort* __restrict__ Bl,     // [HD][K]
    const float*  __restrict__ bias,   // null if none
    float*        __restrict__ Cf,     // fp32 out (null if unused)
    ushort*       __restrict__ Cb,     // bf16 out (null if unused)
    const float*  __restrict__ att_s, const float* __restrict__ att_d,
    float* __restrict__ as_, float* __restrict__ ad_,
    int M)
{
    constexpr int BM = 128, BK = 32;
    constexpr int LDW = 40;                       // LDS row stride (bf16 units)
    __shared__ ushort Ah[BM * LDW];
    __shared__ ushort Al[BM * LDW];

    const int tid  = threadIdx.x;
    const int lane = tid & 63;
    const int wid  = tid >> 6;
    const int blockRow = blockIdx.x * BM;

    const int srow  = tid >> 1;                   // staging: row, half-row
    const int shalf = tid & 1;

    const int fl = lane & 15;                     // frag row (A) / col (B)
    const int fg = lane >> 4;                     // frag k-group

    f32x4 acc[2][8] = {};

    for (int kt = 0; kt < K / BK; ++kt) {
        {
            const int gr = blockRow + srow;
            float v[16];
            if (gr < M) {
                const float* ap = A + (size_t)gr * K + kt * BK + shalf * 16;
                #pragma unroll
                for (int u = 0; u < 4; ++u) {
                    float4 t = *reinterpret_cast<const float4*>(ap + u * 4);
                    v[u*4+0] = t.x; v[u*4+1] = t.y; v[u*4+2] = t.z; v[u*4+3] = t.w;
                }
            } else {
                #pragma unroll
                for (int u = 0; u < 16; ++u) v[u] = 0.f;
            }
            uint32_t hw[8], lw[8];
            #pragma unroll
            for (int u = 0; u < 8; ++u) {
                ushort h0 = f2bf(v[2*u]),   h1 = f2bf(v[2*u+1]);
                ushort l0 = f2bf(v[2*u]   - bf2f(h0));
                ushort l1 = f2bf(v[2*u+1] - bf2f(h1));
                hw[u] = (uint32_t)h0 | ((uint32_t)h1 << 16);
                lw[u] = (uint32_t)l0 | ((uint32_t)l1 << 16);
            }
            uint32_t* dh = reinterpret_cast<uint32_t*>(&Ah[srow * LDW + shalf * 16]);
            uint32_t* dl = reinterpret_cast<uint32_t*>(&Al[srow * LDW + shalf * 16]);
            *reinterpret_cast<uint4*>(dh)     = make_uint4(hw[0], hw[1], hw[2], hw[3]);
            *reinterpret_cast<uint4*>(dh + 4) = make_uint4(hw[4], hw[5], hw[6], hw[7]);
            *reinterpret_cast<uint4*>(dl)     = make_uint4(lw[0], lw[1], lw[2], lw[3]);
            *reinterpret_cast<uint4*>(dl + 4) = make_uint4(lw[4], lw[5], lw[6], lw[7]);
        }
        __syncthreads();

        s16x8 a_h[2], a_l[2];
        #pragma unroll
        for (int rt = 0; rt < 2; ++rt) {
            int r = wid * 32 + rt * 16 + fl;
            a_h[rt] = *reinterpret_cast<const s16x8*>(&Ah[r * LDW + fg * 8]);
            a_l[rt] = *reinterpret_cast<const s16x8*>(&Al[r * LDW + fg * 8]);
        }

        #pragma unroll
        for (int ct = 0; ct < 8; ++ct) {
            const size_t boff = (size_t)(ct * 16 + fl) * K + kt * BK + fg * 8;
            s16x8 b_h = *reinterpret_cast<const s16x8*>(Bh + boff);
            s16x8 b_l = *reinterpret_cast<const s16x8*>(Bl + boff);
            #pragma unroll
            for (int rt = 0; rt < 2; ++rt) {
                acc[rt][ct] = __builtin_amdgcn_mfma_f32_16x16x32_bf16(a_h[rt], b_h, acc[rt][ct], 0, 0, 0);
                acc[rt][ct] = __builtin_amdgcn_mfma_f32_16x16x32_bf16(a_h[rt], b_l, acc[rt][ct], 0, 0, 0);
                acc[rt][ct] = __builtin_amdgcn_mfma_f32_16x16x32_bf16(a_l[rt], b_h, acc[rt][ct], 0, 0, 0);
            }
        }
        __syncthreads();
    }

    float bval[8];
    #pragma unroll
    for (int ct = 0; ct < 8; ++ct) bval[ct] = bias ? bias[ct * 16 + fl] : 0.f;
    float asv[8], adv[8];
    if (ATT) {
        #pragma unroll
        for (int ct = 0; ct < 8; ++ct) {
            asv[ct] = att_s[ct * 16 + fl];
            adv[ct] = att_d[ct * 16 + fl];
        }
    }

    #pragma unroll
    for (int rt = 0; rt < 2; ++rt) {
        const int rbase = blockRow + wid * 32 + rt * 16 + fg * 4;
        #pragma unroll
        for (int r = 0; r < 4; ++r) {
            const int row = rbase + r;
            const bool ok = row < M;
            float sv = 0.f, dv = 0.f;
            #pragma unroll
            for (int ct = 0; ct < 8; ++ct) {
                float val = acc[rt][ct][r] + bval[ct];
                if (ATT) { sv = fmaf(val, asv[ct], sv); dv = fmaf(val, adv[ct], dv); }
                if (ok) {
                    if (Cf) Cf[(size_t)row * HD + ct * 16 + fl] = val;
                    if (Cb) Cb[(size_t)row * HD + ct * 16 + fl] = f2bf(val);
                }
            }
            if (ATT) {
                #pragma unroll
                for (int o = 1; o < 16; o <<= 1) {
                    sv += __shfl_xor(sv, o);
                    dv += __shfl_xor(dv, o);
                }
                if (fl == 0 && ok) { as_[row] = sv; ad_[row] = dv; }
            }
        }
    }
}

// ---------------------------------------------- fused softmax-aggregation

__global__ __launch_bounds__(256) void k_agg(const ushort* __restrict__ hpb,
                                             float* __restrict__ h,
                                             const float* __restrict__ as_,
                                             const float* __restrict__ ad_,
                                             const int* __restrict__ row_ptr,
                                             const int* __restrict__ col,
                                             const float* __restrict__ wsrt,
                                             const float* __restrict__ bias,
                                             float* __restrict__ out, int mode) {
    int wave = (blockIdx.x * blockDim.x + threadIdx.x) >> 6;
    int lane = threadIdx.x & 63;
    if (wave >= NN) return;
    const int d = wave;
    const int beg = row_ptr[d], end = row_ptr[d + 1];
    const float adv = ad_[d];

    float mloc = -INFINITY;
    for (int p = beg + lane; p < end; p += 64) {
        float l = as_[col[p]] + adv;
        l = (l >= 0.f) ? l : NEG_SLOPE * l;
        mloc = fmaxf(mloc, l);
    }
    #pragma unroll
    for (int o = 32; o > 0; o >>= 1) mloc = fmaxf(mloc, __shfl_xor(mloc, o));
    const float m = (end > beg) ? mloc : 0.f;

    float ax = 0.f, ay = 0.f, dloc = 0.f;
    for (int base = beg; base < end; base += 64) {
        const int n = min(64, end - base);
        int   s = 0;
        float w = 0.f;
        if (lane < n) {
            s = col[base + lane];
            float l = as_[s] + adv;
            l = (l >= 0.f) ? l : NEG_SLOPE * l;
            w = __expf(l - m) * wsrt[base + lane];
        }
        dloc += w;

        int i = 0;
        for (; i + 3 < n; i += 4) {
            float w0 = __shfl(w, i),     w1 = __shfl(w, i + 1);
            float w2 = __shfl(w, i + 2), w3 = __shfl(w, i + 3);
            int   s0 = __shfl(s, i),     s1 = __shfl(s, i + 1);
            int   s2 = __shfl(s, i + 2), s3 = __shfl(s, i + 3);
            uint32_t p0 = *reinterpret_cast<const uint32_t*>(hpb + (size_t)s0 * HD + lane * 2);
            uint32_t p1 = *reinterpret_cast<const uint32_t*>(hpb + (size_t)s1 * HD + lane * 2);
            uint32_t p2 = *reinterpret_cast<const uint32_t*>(hpb + (size_t)s2 * HD + lane * 2);
            uint32_t p3 = *reinterpret_cast<const uint32_t*>(hpb + (size_t)s3 * HD + lane * 2);
            ax = fmaf(w0, bf2f((ushort)p0), ax); ay = fmaf(w0, bf2f((ushort)(p0 >> 16)), ay);
            ax = fmaf(w1, bf2f((ushort)p1), ax); ay = fmaf(w1, bf2f((ushort)(p1 >> 16)), ay);
            ax = fmaf(w2, bf2f((ushort)p2), ax); ay = fmaf(w2, bf2f((ushort)(p2 >> 16)), ay);
            ax = fmaf(w3, bf2f((ushort)p3), ax); ay = fmaf(w3, bf2f((ushort)(p3 >> 16)), ay);
        }
        for (; i < n; ++i) {
            float wi = __shfl(w, i);
            int   si = __shfl(s, i);
            uint32_t pv = *reinterpret_cast<const uint32_t*>(hpb + (size_t)si * HD + lane * 2);
            ax = fmaf(wi, bf2f((ushort)pv), ax); ay = fmaf(wi, bf2f((ushort)(pv >> 16)), ay);
        }
    }
    #pragma unroll
    for (int o = 32; o > 0; o >>= 1) dloc += __shfl_xor(dloc, o);

    const float inv = 1.f / (dloc + 1e-16f);
    const float r0 = ax * inv + bias[lane * 2];
    const float r1 = ay * inv + bias[lane * 2 + 1];

    const size_t off = (size_t)d * HD + lane * 2;
    if (mode == 2) {
        float2 o = *reinterpret_cast<float2*>(out + off);
        o.x = fmaxf(o.x, r0); o.y = fmaxf(o.y, r1);
        *reinterpret_cast<float2*>(out + off) = o;
    } else {
        float2 hv = *reinterpret_cast<float2*>(h + off);
        hv.x += r0; hv.y += r1;
        *reinterpret_cast<float2*>(h + off) = hv;
        if (mode == 0) {
            *reinterpret_cast<float2*>(out + off) = hv;
        } else {
            float2 o = *reinterpret_cast<float2*>(out + off);
            o.x = fmaxf(o.x, hv.x); o.y = fmaxf(o.y, hv.y);
            *reinterpret_cast<float2*>(out + off) = o;
        }
    }
}

// ---------------------------------------------------------------- launch

extern "C" void kernel_launch(void* const* d_in, const int* in_sizes, int n_in,
                              void* d_out, int out_size, void* d_ws, size_t ws_size,
                              hipStream_t stream) {
    const float* x        = (const float*)d_in[0];          // [NN][FIN]
    const int*   ei       = (const int*)d_in[1];            // [2][NE]
    const float* ew       = (const float*)d_in[2];          // [NE]
    /* d_in[3] = numNode scalar = NN */
    const float* Wlin     = (const float*)d_in[4];          // [FIN][HD]
    const float* blin     = (const float*)d_in[5];          // [HD]
    const float* Wc       = (const float*)d_in[6];          // [3][HD][HD]
    const float* att_src  = (const float*)d_in[7];          // [3][HD]
    const float* att_dst  = (const float*)d_in[8];          // [3][HD]
    const float* bias_c   = (const float*)d_in[9];          // [3][HD]
    float* out = (float*)d_out;                              // [NN][HD]

    const int* src = ei;
    const int* dst = ei + NE;

    // workspace layout (16B-aligned blocks, ~52 MB)
    char* w = (char*)d_ws;
    float*  h       = (float*)w;   w += (size_t)NN * HD * 4;
    ushort* hpb     = (ushort*)w;  w += (size_t)NN * HD * 2;
    float*  as_     = (float*)w;   w += (size_t)NN * 4;
    float*  ad_     = (float*)w;   w += (size_t)NN * 4;
    int*    row_ptr = (int*)w;     w += (size_t)(NN + 4) * 4;
    int*    col     = (int*)w;     w += (size_t)NE * 4;
    float*  wsrt    = (float*)w;   w += (size_t)NE * 4;
    uint2*  epk     = (uint2*)w;   w += (size_t)NE * 8;
    int*    bhist   = (int*)w;     w += (size_t)NCH * NBK * 4;
    int*    bbeg    = (int*)w;     w += (size_t)(NBK + 4) * 4;
    ushort* WTh     = (ushort*)w;  w += (size_t)(HD * FIN + 3 * HD * HD) * 2;
    ushort* WTl     = (ushort*)w;  w += (size_t)(HD * FIN + 3 * HD * HD) * 2;
    ushort* WlinTh = WTh,            *WlinTl = WTl;
    ushort* WcTh   = WTh + HD * FIN, *WcTl   = WTl + HD * FIN;

    const int TB = 256;
    const int nblk_w = (NN * 64 + TB - 1) / TB;      // one wave per node
    const int nblk_g = (NN + 127) / 128;             // 391

    // ---- weight transpose + split (tiny) ----
    k_split<<<(HD * FIN + TB - 1) / TB, TB, 0, stream>>>(Wlin, WlinTh, WlinTl, FIN);
    for (int l = 0; l < 3; ++l)
        k_split<<<(HD * HD + TB - 1) / TB, TB, 0, stream>>>(
            Wc + (size_t)l * HD * HD, WcTh + (size_t)l * HD * HD,
            WcTl + (size_t)l * HD * HD, HD);

    // ---- CSR build (atomic-reservation-free binning) ----
    k_bhist<<<NCH, 1024, 0, stream>>>(dst, bhist);
    k_bscan<<<1, 256, 0, stream>>>(bhist, bbeg, row_ptr);
    k_binscatter<<<NCH, 1024, 0, stream>>>(src, dst, ew, bhist, epk);
    k_build<<<NBK, 256, 0, stream>>>(epk, bbeg, row_ptr, col, wsrt);

    // ---- input projection: h = x @ Wlin + blin (fp32 out) ----
    k_gemm_mfma<FIN, false><<<nblk_g, TB, 0, stream>>>(
        x, WlinTh, WlinTl, blin, h, nullptr, nullptr, nullptr, nullptr, nullptr, NN);

    // ---- 3 GAT layers ----
    for (int layer = 0; layer < 3; ++layer) {
        k_gemm_mfma<HD, true><<<nblk_g, TB, 0, stream>>>(
            h, WcTh + (size_t)layer * HD * HD, WcTl + (size_t)layer * HD * HD,
            nullptr, nullptr, hpb,
            att_src + layer * HD, att_dst + layer * HD, as_, ad_, NN);
        int mode = (layer == 0) ? 0 : (layer == 2 ? 2 : 1);
        k_agg<<<nblk_w, TB, 0, stream>>>(hpb, h, as_, ad_, row_ptr, col, wsrt,
                                         bias_c + layer * HD, out, mode);
    }
}